// Round 5
// baseline (114.642 us; speedup 1.0000x reference)
//
#include <hip/hip_runtime.h>

#define NN 50
#define D 64
#define GRP 10
#define E 4   // batch elements per wave (amortize GEMV weight reads)

__device__ __forceinline__ float wave_sum64(float x) {
#pragma unroll
  for (int off = 32; off > 0; off >>= 1)
    x += __shfl_xor(x, off, 64);
  return x;
}

__device__ __forceinline__ float readlane_f(float v, int l) {
  return __uint_as_float(__builtin_amdgcn_readlane(__float_as_uint(v), l));
}

// Load group g's 10 neighbor rows (lane = dim). All indices compile-time.
__device__ __forceinline__ void load_grp(float (&buf)[GRP],
                                         const int* __restrict__ adjb,
                                         const float* __restrict__ ent_tab,
                                         int g, int lane) {
#pragma unroll
  for (int i = 0; i < GRP; ++i) {
    int t = adjb[g * GRP + i];      // wave-uniform -> s_load
    t = t < 0 ? 0 : t;
    buf[i] = ent_tab[(long)t * D + lane];   // coalesced 256B row
  }
}

// Score + exp + accumulate for one group. buf stays in registers.
__device__ __forceinline__ void proc_grp(const float (&buf)[GRP],
                                         float Wn, float base,
                                         float& l0, float& l1, float& na) {
  float ex[GRP];
#pragma unroll
  for (int i = 0; i < GRP; ++i) {   // 10 independent reduce chains (ILP)
    float t = wave_sum64(buf[i] * Wn) + base;
    t = t > 0.f ? t : 0.2f * t;     // leaky_relu(0.2)
    ex[i] = __expf(t - 8.0f);       // fixed-max softmax: scores bounded ~[-2,8]
  }
#pragma unroll
  for (int i = 0; i < GRP; ++i) {
    if (i & 1) l1 += ex[i]; else l0 += ex[i];
    na = fmaf(ex[i], buf[i], na);
  }
}

// Full attention for one element: returns unnormalized-then-normalized
// neighbor_attn[lane]. Double-buffered named register arrays (R3-proven).
__device__ __forceinline__ float attn_one(const int* __restrict__ adjb,
                                          const float* __restrict__ ent_tab,
                                          float Wn, float base, int lane) {
  float na = 0.f, l0 = 0.f, l1 = 0.f;
  float A[GRP], Bv[GRP];
  load_grp(A,  adjb, ent_tab, 0, lane);
  load_grp(Bv, adjb, ent_tab, 1, lane);
  proc_grp(A,  Wn, base, l0, l1, na);
  load_grp(A,  adjb, ent_tab, 2, lane);
  proc_grp(Bv, Wn, base, l0, l1, na);
  load_grp(Bv, adjb, ent_tab, 3, lane);
  proc_grp(A,  Wn, base, l0, l1, na);
  load_grp(A,  adjb, ent_tab, 4, lane);
  proc_grp(Bv, Wn, base, l0, l1, na);
  proc_grp(A,  Wn, base, l0, l1, na);
  return na / (l0 + l1);
}

__global__ __launch_bounds__(256, 4) void kgat_fwd(
    const int* __restrict__ user_idx, const int* __restrict__ item_idx,
    const int* __restrict__ adj,
    const float* __restrict__ user_tab, const float* __restrict__ item_tab,
    const float* __restrict__ ent_tab,
    const float* __restrict__ attn_W, const float* __restrict__ attn_b,
    const float* __restrict__ W1, const float* __restrict__ b1,
    const float* __restrict__ W2, const float* __restrict__ b2,
    const float* __restrict__ cW, const float* __restrict__ cb,
    const float* __restrict__ oW, const float* __restrict__ ob,
    float* __restrict__ out, int B)
{
  const int lane = threadIdx.x & 63;
  const int wv   = threadIdx.x >> 6;
  const int b0   = (blockIdx.x * 4 + wv) * E;   // 4 elements per wave
  if (b0 >= B) return;

  const float Wi = attn_W[lane];
  const float Wn = attn_W[D + lane];
  const float ab = attn_b[0];

  // ---- per-element: user/item rows + attention-refined neighbor vector ----
  float user[E], item[E], na[E];
#pragma unroll
  for (int e = 0; e < E; ++e) {
    const int b = b0 + e;
    user[e] = user_tab[(long)user_idx[b] * D + lane];
    item[e] = item_tab[(long)item_idx[b] * D + lane];
  }
#pragma unroll
  for (int e = 0; e < E; ++e) {
    const float base = wave_sum64(item[e] * Wi) + ab;   // wave-uniform
    na[e] = attn_one(adj + (long)(b0 + e) * NN, ent_tab, Wn, base, lane);
  }

  // ---- h = relu(na @ W1 + b1): weight column loaded ONCE for 4 elements ----
  float acc0[E], acc1[E];
#pragma unroll
  for (int e = 0; e < E; ++e) { acc0[e] = b1[lane]; acc1[e] = 0.f; }
#pragma unroll
  for (int d = 0; d < D; d += 2) {
    const float w0 = W1[(d + 0) * D + lane];
    const float w1 = W1[(d + 1) * D + lane];
#pragma unroll
    for (int e = 0; e < E; ++e) {
      acc0[e] = fmaf(readlane_f(na[e], d + 0), w0, acc0[e]);
      acc1[e] = fmaf(readlane_f(na[e], d + 1), w1, acc1[e]);
    }
  }
  float h[E];
#pragma unroll
  for (int e = 0; e < E; ++e) h[e] = fmaxf(acc0[e] + acc1[e], 0.f);

  // ---- r = h @ W2 + b2 ----
#pragma unroll
  for (int e = 0; e < E; ++e) { acc0[e] = b2[lane]; acc1[e] = 0.f; }
#pragma unroll
  for (int d = 0; d < D; d += 2) {
    const float w0 = W2[(d + 0) * D + lane];
    const float w1 = W2[(d + 1) * D + lane];
#pragma unroll
    for (int e = 0; e < E; ++e) {
      acc0[e] = fmaf(readlane_f(h[e], d + 0), w0, acc0[e]);
      acc1[e] = fmaf(readlane_f(h[e], d + 1), w1, acc1[e]);
    }
  }
  float r[E];
#pragma unroll
  for (int e = 0; e < E; ++e) r[e] = acc0[e] + acc1[e];

  // ---- f = relu([item, r] @ cW + cb) ----
#pragma unroll
  for (int e = 0; e < E; ++e) { acc0[e] = cb[lane]; acc1[e] = 0.f; }
#pragma unroll
  for (int k = 0; k < D; k += 2) {
    const float w0 = cW[(k + 0) * D + lane];
    const float w1 = cW[(k + 1) * D + lane];
#pragma unroll
    for (int e = 0; e < E; ++e) {
      acc0[e] = fmaf(readlane_f(item[e], k + 0), w0, acc0[e]);
      acc1[e] = fmaf(readlane_f(item[e], k + 1), w1, acc1[e]);
    }
  }
#pragma unroll
  for (int k = 0; k < D; k += 2) {
    const float w0 = cW[(D + k + 0) * D + lane];
    const float w1 = cW[(D + k + 1) * D + lane];
#pragma unroll
    for (int e = 0; e < E; ++e) {
      acc0[e] = fmaf(readlane_f(r[e], k + 0), w0, acc0[e]);
      acc1[e] = fmaf(readlane_f(r[e], k + 1), w1, acc1[e]);
    }
  }

  // ---- score = dot([user, f], oW) + ob ----
  const float oWu = oW[lane];
  const float oWf = oW[D + lane];
  const float ob0 = ob[0];
#pragma unroll
  for (int e = 0; e < E; ++e) {
    const float f = fmaxf(acc0[e] + acc1[e], 0.f);
    const float sc = wave_sum64(fmaf(user[e], oWu, f * oWf));
    if (lane == 0) out[b0 + e] = sc + ob0;
  }
}

extern "C" void kernel_launch(void* const* d_in, const int* in_sizes, int n_in,
                              void* d_out, int out_size, void* d_ws, size_t ws_size,
                              hipStream_t stream) {
  const int*   user_idx = (const int*)d_in[0];
  const int*   item_idx = (const int*)d_in[1];
  const int*   adj      = (const int*)d_in[2];
  const float* user_tab = (const float*)d_in[3];
  const float* item_tab = (const float*)d_in[4];
  const float* ent_tab  = (const float*)d_in[5];
  const float* attn_W   = (const float*)d_in[6];
  const float* attn_b   = (const float*)d_in[7];
  const float* W1       = (const float*)d_in[8];
  const float* b1       = (const float*)d_in[9];
  const float* W2       = (const float*)d_in[10];
  const float* b2       = (const float*)d_in[11];
  const float* cW       = (const float*)d_in[12];
  const float* cb       = (const float*)d_in[13];
  const float* oW       = (const float*)d_in[14];
  const float* ob       = (const float*)d_in[15];
  float* out = (float*)d_out;

  const int B = in_sizes[0];
  const int blocks = (B + 4 * E - 1) / (4 * E);  // 4 waves x E elements each
  kgat_fwd<<<blocks, 256, 0, stream>>>(user_idx, item_idx, adj,
                                       user_tab, item_tab, ent_tab,
                                       attn_W, attn_b, W1, b1, W2, b2,
                                       cW, cb, oW, ob, out, B);
}